// Round 11
// baseline (713.646 us; speedup 1.0000x reference)
//
#include <hip/hip_runtime.h>

#define B_    32
#define N_    64
#define IN_   2048
#define D_    32
#define K_    16
#define CELLS  ((size_t)B_*N_*D_)      /* 65536 */
#define WELEMS ((size_t)N_*IN_*D_*K_)  /* 67108864 */
#define UH_ELEMS ((size_t)B_*IN_*N_*D_) /* 134217728 */
#define UH_BYTES (UH_ELEMS*2)          /* 256 MB */
#define T_B    8                        /* i's per tile (uhatA and routeB) */
#define NTILE_B (IN_/T_B)               /* 256 */
#define NBLK_B  (NTILE_B*8)             /* 2048 */

// softmax_e(v * INV_LOG2) == 2^((v-max) * (1/ln2)^2)
#define SM_SCALE 2.0813689810056077f

// ---- bf16 helpers (RNE) ----
__device__ __forceinline__ unsigned int rb(float f) {
    unsigned int u = __float_as_uint(f);
    return (u + 0x7fffu + ((u >> 16) & 1u)) >> 16;
}
__device__ __forceinline__ float blo(unsigned int u) { return __uint_as_float(u << 16); }
__device__ __forceinline__ float bhi(unsigned int u) { return __uint_as_float(u & 0xffff0000u); }

__device__ __forceinline__ float dot8(uint4 q, const float* o) {
    return blo(q.x)*o[0] + bhi(q.x)*o[1] + blo(q.y)*o[2] + bhi(q.y)*o[3]
         + blo(q.z)*o[4] + bhi(q.z)*o[5] + blo(q.w)*o[6] + bhi(q.w)*o[7];
}
__device__ __forceinline__ void acc8(float* s, uint4 q, float c) {
    s[0] += c*blo(q.x); s[1] += c*bhi(q.x); s[2] += c*blo(q.y); s[3] += c*bhi(q.y);
    s[4] += c*blo(q.z); s[5] += c*bhi(q.z); s[6] += c*blo(q.w); s[7] += c*bhi(q.w);
}

// -----------------------------------------------------------------------------
// zero_kernel: os = 0. Replaces hipMemsetAsync -- R10 profile showed the
// in-graph memset node costs ~155us/replay (blit/queue-sync overhead).
// -----------------------------------------------------------------------------
__global__ __launch_bounds__(256)
void zero_kernel(float4* __restrict__ os)
{
    os[blockIdx.x * 256 + threadIdx.x] = float4{0.f, 0.f, 0.f, 0.f};
}

// -----------------------------------------------------------------------------
// uhatA_kernel: u_hat[b][i][n][d] = sum_k W[n,i,d,k]*x[b,i,k] (bf16 store),
// FUSED with routing pass 0 (c uniform = 1/64): accumulates s0[b] over the
// block's 8-i tile and writes pass-0 partials in finishB's layout.
// Block=(i-tile of 8, n-chunk of 8); thread=(n,d). W read ONCE chip-wide,
// coalesced; x block-uniform -> scalar loads. ~70 VGPR.
// -----------------------------------------------------------------------------
__global__ __launch_bounds__(256, 1)
void uhatA_kernel(const float* __restrict__ x, const float* __restrict__ W,
                  unsigned short* __restrict__ uhat, float* __restrict__ part)
{
    const int tid   = threadIdx.x;
    const int itile = blockIdx.x >> 3;
    const int chunk = blockIdx.x & 7;
    const int n     = chunk * 8 + (tid >> 5);
    const int d     = tid & 31;
    const int i0    = itile * T_B;

    float s0[B_];
    #pragma unroll
    for (int b = 0; b < B_; ++b) s0[b] = 0.f;

    #pragma unroll 1
    for (int ii = 0; ii < T_B; ++ii) {
        const int i = i0 + ii;
        const float4* wp = (const float4*)(W + (((size_t)n * IN_ + i) * D_ + d) * K_);
        const float4 w0 = wp[0], w1 = wp[1], w2 = wp[2], w3 = wp[3];
        const float* xb = x + (size_t)i * K_;
        unsigned short* up = uhat + (size_t)i * (N_ * D_) + n * D_ + d;

        #pragma unroll
        for (int b = 0; b < B_; ++b) {
            const float* xr = xb + (size_t)b * (IN_ * K_);   // block-uniform -> s_load
            const float4 x0 = *(const float4*)(xr);
            const float4 x1 = *(const float4*)(xr + 4);
            const float4 x2 = *(const float4*)(xr + 8);
            const float4 x3 = *(const float4*)(xr + 12);
            const float uh = w0.x*x0.x + w0.y*x0.y + w0.z*x0.z + w0.w*x0.w
                           + w1.x*x1.x + w1.y*x1.y + w1.z*x1.z + w1.w*x1.w
                           + w2.x*x2.x + w2.y*x2.y + w2.z*x2.z + w2.w*x2.w
                           + w3.x*x3.x + w3.y*x3.y + w3.z*x3.z + w3.w*x3.w;
            up[(size_t)b * (IN_ * (size_t)(N_ * D_))] = (unsigned short)rb(uh);
            s0[b] += uh;
        }
    }

    // pass-0 partials (c = 1/64), layout: part[itile*CELLS + (b*N+n)*D + d]
    float* myp = part + (size_t)itile * CELLS + (size_t)n * D_ + d;
    #pragma unroll
    for (int b = 0; b < B_; ++b)
        myp[(size_t)b * (N_ * D_)] = s0[b] * (1.0f / 64.0f);
}

// -----------------------------------------------------------------------------
// routeB_kernel: routing pass reading u_hat (bf16, single-touch, coalesced).
// Thread=(b-in-group, n): 256 thr = 4b x 64n; block=(i-tile of 8, b-group).
// logit = thread-local dot over d (no shuffles); softmax over n = one 64-lane
// butterfly; s_acc[32] in regs.
// -----------------------------------------------------------------------------
__global__ __launch_bounds__(256, 1)
void routeB_kernel(const unsigned short* __restrict__ uhat,
                   const float* __restrict__ os, float* __restrict__ part)
{
    const int tid  = threadIdx.x;
    const int jb   = tid >> 6;          // wave = batch-in-group
    const int n    = tid & 63;          // lane = n
    const int tile = blockIdx.x >> 3;
    const int bg   = blockIdx.x & 7;
    const int b    = bg * 4 + jb;
    const int i0   = tile * T_B;

    float s_acc[D_];
    #pragma unroll
    for (int d = 0; d < D_; ++d) s_acc[d] = 0.f;

    float osr[D_];
    {
        const float4* op = (const float4*)(os + ((size_t)b * N_ + n) * D_);
        #pragma unroll
        for (int d4 = 0; d4 < 8; ++d4) *(float4*)&osr[d4 * 4] = op[d4];
    }

    const unsigned short* up = uhat + ((size_t)b * IN_ + i0) * (N_ * D_) + n * D_;

    #pragma unroll 2
    for (int ii = 0; ii < T_B; ++ii) {
        const uint4 q0 = *(const uint4*)(up);
        const uint4 q1 = *(const uint4*)(up + 8);
        const uint4 q2 = *(const uint4*)(up + 16);
        const uint4 q3 = *(const uint4*)(up + 24);
        up += N_ * D_;

        float t = dot8(q0, osr) + dot8(q1, osr + 8)
                + dot8(q2, osr + 16) + dot8(q3, osr + 24);
        float mx = t;
        #pragma unroll
        for (int m = 1; m < 64; m <<= 1) mx = fmaxf(mx, __shfl_xor(mx, m, 64));
        const float e = exp2f((t - mx) * SM_SCALE);
        float sum = e;
        #pragma unroll
        for (int m = 1; m < 64; m <<= 1) sum += __shfl_xor(sum, m, 64);
        const float c = e / sum;
        acc8(s_acc, q0, c); acc8(s_acc + 8,  q1, c);
        acc8(s_acc + 16, q2, c); acc8(s_acc + 24, q3, c);
    }

    float4* myp = (float4*)(part + (size_t)tile * CELLS + ((size_t)b * N_ + n) * D_);
    #pragma unroll
    for (int d4 = 0; d4 < 8; ++d4) {
        float4 v;
        v.x = s_acc[d4*4 + 0]; v.y = s_acc[d4*4 + 1];
        v.z = s_acc[d4*4 + 2]; v.w = s_acc[d4*4 + 3];
        myp[d4] = v;
    }
}

// -----------------------------------------------------------------------------
// finishB_kernel: s = sum over NTILE_B tile-partials; out = squash(s);
// FINAL=false: os += out; FINAL=true: write d_out.
// -----------------------------------------------------------------------------
template<bool FINAL>
__global__ __launch_bounds__(256)
void finishB_kernel(const float* __restrict__ part,
                    float* __restrict__ os, float* __restrict__ out)
{
    const int gid = blockIdx.x * 256 + threadIdx.x;   // 0..65535 = b*2048+n*32+d
    float v = 0.f;
    for (int t = 0; t < NTILE_B; ++t) v += part[(size_t)t * CELLS + gid];
    float sq = v * v;
    #pragma unroll
    for (int m = 1; m < 32; m <<= 1) sq += __shfl_xor(sq, m, 64);  // sum over d
    const float scale = sqrtf(sq) / (1.0f + sq);
    const float o = v * scale;
    if (FINAL) out[gid] = o;
    else       os[gid] += o;
}

// =============================================================================
// ===== R8 fallback path (582us) -- used only if ws < ~320 MB =================
// =============================================================================
#define BH    4
#define NBG   (B_/BH)
#define ITILE 8
#define NTILE (IN_/ITILE)
#define NBLK  (NTILE*NBG)
#define PCELLS ((size_t)BH*N_*D_)

__global__ __launch_bounds__(256)
void convert_kernel(const float4* __restrict__ W, uint4* __restrict__ W16)
{
    const size_t n8 = WELEMS / 8;
    const size_t stride = (size_t)gridDim.x * 256;
    for (size_t i = (size_t)blockIdx.x * 256 + threadIdx.x; i < n8; i += stride) {
        const float4 a = W[2 * i], b = W[2 * i + 1];
        uint4 o;
        o.x = rb(a.x) | (rb(a.y) << 16);
        o.y = rb(a.z) | (rb(a.w) << 16);
        o.z = rb(b.x) | (rb(b.y) << 16);
        o.w = rb(b.z) | (rb(b.w) << 16);
        W16[i] = o;
    }
}

template<bool FIRST>
__global__ __launch_bounds__(256, 1)
void route16_kernel(const float* __restrict__ x, const unsigned short* __restrict__ W16,
                    const float* __restrict__ os, float* __restrict__ part)
{
    __shared__ unsigned short uh_s[N_][D_][BH];
    __shared__ float logit_s[BH][N_];

    const int tid  = threadIdx.x;
    const int w    = tid >> 6;
    const int l    = tid & 63;
    const int d    = l & 31;
    const int hi   = l >> 5;
    const int slot = w * 2 + hi;

    const int virt = (blockIdx.x & 7) * (NBLK / 8) + (blockIdx.x >> 3);
    const int tile = virt / NBG;
    const int bg   = virt % NBG;
    const int b0   = bg * BH;
    const int i0   = tile * ITILE;

    float s_acc[8][BH];
    #pragma unroll
    for (int r = 0; r < 8; ++r)
        #pragma unroll
        for (int jb = 0; jb < BH; ++jb) s_acc[r][jb] = 0.f;

    const unsigned short* wb = W16 + (((size_t)slot * IN_ + i0) * D_ + d) * K_;

    for (int ii = 0; ii < ITILE; ++ii) {
        const float* xb = x + (size_t)b0 * (IN_ * K_) + (size_t)(i0 + ii) * K_;

        #pragma unroll
        for (int r = 0; r < 8; ++r) {
            const int n = r * 8 + slot;
            const unsigned short* wr = wb + (size_t)r * (8ull * IN_ * D_ * K_)
                                          + (size_t)ii * (D_ * K_);
            const uint4 plo = *(const uint4*)(wr);
            const uint4 phi = *(const uint4*)(wr + 8);
            float wf[16];
            wf[ 0]=blo(plo.x); wf[ 1]=bhi(plo.x); wf[ 2]=blo(plo.y); wf[ 3]=bhi(plo.y);
            wf[ 4]=blo(plo.z); wf[ 5]=bhi(plo.z); wf[ 6]=blo(plo.w); wf[ 7]=bhi(plo.w);
            wf[ 8]=blo(phi.x); wf[ 9]=bhi(phi.x); wf[10]=blo(phi.y); wf[11]=bhi(phi.y);
            wf[12]=blo(phi.z); wf[13]=bhi(phi.z); wf[14]=blo(phi.w); wf[15]=bhi(phi.w);

            float uh[BH];
            #pragma unroll
            for (int jb = 0; jb < BH; ++jb) {
                const float4 x0 = *(const float4*)(xb + (size_t)jb * (IN_ * K_) + 0);
                const float4 x1 = *(const float4*)(xb + (size_t)jb * (IN_ * K_) + 4);
                const float4 x2 = *(const float4*)(xb + (size_t)jb * (IN_ * K_) + 8);
                const float4 x3 = *(const float4*)(xb + (size_t)jb * (IN_ * K_) + 12);
                uh[jb] = wf[ 0]*x0.x + wf[ 1]*x0.y + wf[ 2]*x0.z + wf[ 3]*x0.w
                       + wf[ 4]*x1.x + wf[ 5]*x1.y + wf[ 6]*x1.z + wf[ 7]*x1.w
                       + wf[ 8]*x2.x + wf[ 9]*x2.y + wf[10]*x2.z + wf[11]*x2.w
                       + wf[12]*x3.x + wf[13]*x3.y + wf[14]*x3.z + wf[15]*x3.w;
            }

            if (FIRST) {
                #pragma unroll
                for (int jb = 0; jb < BH; ++jb) s_acc[r][jb] += uh[jb];
            } else {
                uint2 pk;
                pk.x = rb(uh[0]) | (rb(uh[1]) << 16);
                pk.y = rb(uh[2]) | (rb(uh[3]) << 16);
                *(uint2*)&uh_s[n][d][0] = pk;
                #pragma unroll
                for (int jb = 0; jb < BH; ++jb) {
                    float t = uh[jb] * os[((size_t)(b0 + jb) * N_ + n) * D_ + d];
                    #pragma unroll
                    for (int m = 1; m < 32; m <<= 1) t += __shfl_xor(t, m, 64);
                    if (d == 0) logit_s[jb][n] = t;
                }
            }
        }

        if (!FIRST) {
            __syncthreads();
            {
                const float v = logit_s[w][l];
                float mx = v;
                #pragma unroll
                for (int m = 1; m < 64; m <<= 1) mx = fmaxf(mx, __shfl_xor(mx, m, 64));
                const float e = exp2f((v - mx) * SM_SCALE);
                float sum = e;
                #pragma unroll
                for (int m = 1; m < 64; m <<= 1) sum += __shfl_xor(sum, m, 64);
                logit_s[w][l] = e / sum;
            }
            __syncthreads();
            #pragma unroll
            for (int r = 0; r < 8; ++r) {
                const int n = r * 8 + slot;
                const uint2 pk = *(const uint2*)&uh_s[n][d][0];
                s_acc[r][0] += logit_s[0][n] * blo(pk.x);
                s_acc[r][1] += logit_s[1][n] * bhi(pk.x);
                s_acc[r][2] += logit_s[2][n] * blo(pk.y);
                s_acc[r][3] += logit_s[3][n] * bhi(pk.y);
            }
            __syncthreads();
        }
    }

    const float scale = FIRST ? (1.0f / 64.0f) : 1.0f;
    float* myp = part + (size_t)virt * PCELLS;
    #pragma unroll
    for (int r = 0; r < 8; ++r) {
        const int n = r * 8 + slot;
        #pragma unroll
        for (int jb = 0; jb < BH; ++jb)
            myp[((size_t)jb * N_ + n) * D_ + d] = s_acc[r][jb] * scale;
    }
}

template<bool FINAL>
__global__ __launch_bounds__(256)
void finish_kernel(const float* __restrict__ part,
                   float* __restrict__ os, float* __restrict__ out)
{
    const int gid = blockIdx.x * 256 + threadIdx.x;
    const int b   = gid >> 11;
    const int rem = gid & 2047;
    const int bg = b >> 2, jb = b & 3;
    const float* p0 = part + (size_t)bg * PCELLS + (size_t)jb * (N_ * D_) + rem;
    float v = 0.f;
    for (int t = 0; t < NTILE; ++t) v += p0[(size_t)t * NBG * PCELLS];
    float sq = v * v;
    #pragma unroll
    for (int m = 1; m < 32; m <<= 1) sq += __shfl_xor(sq, m, 64);
    const float scale = sqrtf(sq) / (1.0f + sq);
    const float o = v * scale;
    if (FINAL) out[gid] = o;
    else       os[gid] += o;
}

extern "C" void kernel_launch(void* const* d_in, const int* in_sizes, int n_in,
                              void* d_out, int out_size, void* d_ws, size_t ws_size,
                              hipStream_t stream)
{
    const float* x = (const float*)d_in[0];
    const float* W = (const float*)d_in[1];
    float* out = (float*)d_out;

    const size_t partB_bytes = (size_t)NTILE_B * CELLS * 4;   // 64 MB
    const size_t need_new    = UH_BYTES + partB_bytes + CELLS * 4;

    if (ws_size >= need_new) {
        unsigned short* uhat = (unsigned short*)d_ws;
        float* part = (float*)((char*)d_ws + UH_BYTES);
        float* os   = part + (size_t)NTILE_B * CELLS;

        zero_kernel<<<CELLS / 1024, 256, 0, stream>>>((float4*)os);
        uhatA_kernel<<<NTILE_B * 8, 256, 0, stream>>>(x, W, uhat, part);  // + pass 0
        finishB_kernel<false><<<CELLS / 256, 256, 0, stream>>>(part, os, nullptr);
        routeB_kernel<<<NBLK_B, 256, 0, stream>>>(uhat, os, part);        // pass 1
        finishB_kernel<false><<<CELLS / 256, 256, 0, stream>>>(part, os, nullptr);
        routeB_kernel<<<NBLK_B, 256, 0, stream>>>(uhat, os, part);        // pass 2
        finishB_kernel<true ><<<CELLS / 256, 256, 0, stream>>>(part, nullptr, out);
        return;
    }

    // ---- R8 fallback (proven) ----
    const size_t w16_bytes = WELEMS * 2;
    unsigned short* W16 = (unsigned short*)d_ws;
    float* part = (float*)((char*)d_ws + w16_bytes);
    float* os   = part + (size_t)NBLK * PCELLS;

    zero_kernel<<<CELLS / 1024, 256, 0, stream>>>((float4*)os);
    convert_kernel<<<2048, 256, 0, stream>>>((const float4*)W, (uint4*)d_ws);

    for (int it = 0; it < 3; ++it) {
        if (it == 0) route16_kernel<true ><<<NBLK, 256, 0, stream>>>(x, W16, os, part);
        else         route16_kernel<false><<<NBLK, 256, 0, stream>>>(x, W16, os, part);
        if (it < 2)  finish_kernel<false><<<CELLS / 256, 256, 0, stream>>>(part, os, nullptr);
        else         finish_kernel<true ><<<CELLS / 256, 256, 0, stream>>>(part, nullptr, out);
    }
}

// Round 12
// 488.608 us; speedup vs baseline: 1.4606x; 1.4606x over previous
//
#include <hip/hip_runtime.h>

#define B_    32
#define N_    64
#define IN_   2048
#define D_    32
#define K_    16
#define CELLS  ((size_t)B_*N_*D_)      /* 65536 */
#define WELEMS ((size_t)N_*IN_*D_*K_)  /* 67108864 */
#define UH_ELEMS ((size_t)B_*IN_*N_*D_) /* 134217728 */
#define UH_BYTES (UH_ELEMS*2)          /* 256 MB */
#define T_B    8                        /* i's per routeB block */
#define NTILE_B (IN_/T_B)               /* 256 */
#define NBLK_B  (NTILE_B*8)             /* 2048 */

// softmax_e(v * INV_LOG2) == 2^((v-max) * (1/ln2)^2)
#define SM_SCALE 2.0813689810056077f

// ---- bf16 helpers (RNE) ----
__device__ __forceinline__ unsigned int rb(float f) {
    unsigned int u = __float_as_uint(f);
    return (u + 0x7fffu + ((u >> 16) & 1u)) >> 16;
}
__device__ __forceinline__ float blo(unsigned int u) { return __uint_as_float(u << 16); }
__device__ __forceinline__ float bhi(unsigned int u) { return __uint_as_float(u & 0xffff0000u); }

__device__ __forceinline__ float dot8(uint4 q, const float* o) {
    return blo(q.x)*o[0] + bhi(q.x)*o[1] + blo(q.y)*o[2] + bhi(q.y)*o[3]
         + blo(q.z)*o[4] + bhi(q.z)*o[5] + blo(q.w)*o[6] + bhi(q.w)*o[7];
}
__device__ __forceinline__ void acc8(float* s, uint4 q, float c) {
    s[0] += c*blo(q.x); s[1] += c*bhi(q.x); s[2] += c*blo(q.y); s[3] += c*bhi(q.y);
    s[4] += c*blo(q.z); s[5] += c*bhi(q.z); s[6] += c*blo(q.w); s[7] += c*bhi(q.w);
}

// -----------------------------------------------------------------------------
// zero_kernel: os = 0 (replaces hipMemsetAsync; R10 showed the in-graph memset
// node costs ~155us/replay; R11 confirmed the fills vanish with this).
// -----------------------------------------------------------------------------
__global__ __launch_bounds__(256)
void zero_kernel(float4* __restrict__ os)
{
    os[blockIdx.x * 256 + threadIdx.x] = float4{0.f, 0.f, 0.f, 0.f};
}

// -----------------------------------------------------------------------------
// uhat_kernel (R10-proven, UNFUSED): u_hat[b][i][n][d] = sum_k W[n,i,d,k]*x[b,i,k]
// stored bf16. Thread=(n,d), block=(i, n-chunk of 8). W read ONCE chip-wide,
// coalesced; x block-uniform -> scalar loads. Light registers (~40 VGPR) ->
// high occupancy. R11 lesson: fusing pass-0 (s0[32] regs) collapses occupancy
// (VGPR 104, occ 23%, 464us) -- do NOT fuse.
// -----------------------------------------------------------------------------
__global__ __launch_bounds__(256, 1)
void uhat_kernel(const float* __restrict__ x, const float* __restrict__ W,
                 unsigned short* __restrict__ uhat)
{
    const int tid   = threadIdx.x;
    const int i     = blockIdx.x >> 3;
    const int chunk = blockIdx.x & 7;
    const int n     = chunk * 8 + (tid >> 5);
    const int d     = tid & 31;

    const float4* wp = (const float4*)(W + (((size_t)n * IN_ + i) * D_ + d) * K_);
    const float4 w0 = wp[0], w1 = wp[1], w2 = wp[2], w3 = wp[3];

    const float* xb = x + (size_t)i * K_;
    unsigned short* up = uhat + (size_t)i * (N_ * D_) + n * D_ + d;

    #pragma unroll 8
    for (int b = 0; b < B_; ++b) {
        const float* xr = xb + (size_t)b * (IN_ * K_);   // block-uniform -> s_load
        const float4 x0 = *(const float4*)(xr);
        const float4 x1 = *(const float4*)(xr + 4);
        const float4 x2 = *(const float4*)(xr + 8);
        const float4 x3 = *(const float4*)(xr + 12);
        const float uh = w0.x*x0.x + w0.y*x0.y + w0.z*x0.z + w0.w*x0.w
                       + w1.x*x1.x + w1.y*x1.y + w1.z*x1.z + w1.w*x1.w
                       + w2.x*x2.x + w2.y*x2.y + w2.z*x2.z + w2.w*x2.w
                       + w3.x*x3.x + w3.y*x3.y + w3.z*x3.z + w3.w*x3.w;
        up[(size_t)b * (IN_ * (size_t)(N_ * D_))] = (unsigned short)rb(uh);
    }
}

// -----------------------------------------------------------------------------
// routeB_kernel: one routing pass reading u_hat (bf16, single-touch).
// Thread=(b-in-group, n): 256 thr = 4b x 64n; block=(i-tile of 8, b-group).
// logit = thread-local dot over d (no shuffles); softmax over n = one 64-lane
// butterfly; s_acc[32] in regs. PASS=false: iteration 0, c = 1/64 uniform.
// -----------------------------------------------------------------------------
template<bool PASS>
__global__ __launch_bounds__(256, 1)
void routeB_kernel(const unsigned short* __restrict__ uhat,
                   const float* __restrict__ os, float* __restrict__ part)
{
    const int tid  = threadIdx.x;
    const int jb   = tid >> 6;          // wave = batch-in-group
    const int n    = tid & 63;          // lane = n
    const int tile = blockIdx.x >> 3;
    const int bg   = blockIdx.x & 7;
    const int b    = bg * 4 + jb;
    const int i0   = tile * T_B;

    float s_acc[D_];
    #pragma unroll
    for (int d = 0; d < D_; ++d) s_acc[d] = 0.f;

    float osr[D_];
    if (PASS) {
        const float4* op = (const float4*)(os + ((size_t)b * N_ + n) * D_);
        #pragma unroll
        for (int d4 = 0; d4 < 8; ++d4) *(float4*)&osr[d4 * 4] = op[d4];
    }

    const unsigned short* up = uhat + ((size_t)b * IN_ + i0) * (N_ * D_) + n * D_;

    #pragma unroll 2
    for (int ii = 0; ii < T_B; ++ii) {
        const uint4 q0 = *(const uint4*)(up);
        const uint4 q1 = *(const uint4*)(up + 8);
        const uint4 q2 = *(const uint4*)(up + 16);
        const uint4 q3 = *(const uint4*)(up + 24);
        up += N_ * D_;

        if (PASS) {
            float t = dot8(q0, osr) + dot8(q1, osr + 8)
                    + dot8(q2, osr + 16) + dot8(q3, osr + 24);
            float mx = t;
            #pragma unroll
            for (int m = 1; m < 64; m <<= 1) mx = fmaxf(mx, __shfl_xor(mx, m, 64));
            const float e = exp2f((t - mx) * SM_SCALE);
            float sum = e;
            #pragma unroll
            for (int m = 1; m < 64; m <<= 1) sum += __shfl_xor(sum, m, 64);
            const float c = e / sum;
            acc8(s_acc, q0, c); acc8(s_acc + 8,  q1, c);
            acc8(s_acc + 16, q2, c); acc8(s_acc + 24, q3, c);
        } else {
            acc8(s_acc, q0, 1.f); acc8(s_acc + 8,  q1, 1.f);
            acc8(s_acc + 16, q2, 1.f); acc8(s_acc + 24, q3, 1.f);
        }
    }

    const float scale = PASS ? 1.f : (1.f / 64.f);
    float4* myp = (float4*)(part + (size_t)tile * CELLS + ((size_t)b * N_ + n) * D_);
    #pragma unroll
    for (int d4 = 0; d4 < 8; ++d4) {
        float4 v;
        v.x = s_acc[d4*4 + 0] * scale; v.y = s_acc[d4*4 + 1] * scale;
        v.z = s_acc[d4*4 + 2] * scale; v.w = s_acc[d4*4 + 3] * scale;
        myp[d4] = v;
    }
}

// -----------------------------------------------------------------------------
// finishB_kernel: s = sum over NTILE_B tile-partials; out = squash(s);
// FINAL=false: os += out; FINAL=true: write d_out.
// -----------------------------------------------------------------------------
template<bool FINAL>
__global__ __launch_bounds__(256)
void finishB_kernel(const float* __restrict__ part,
                    float* __restrict__ os, float* __restrict__ out)
{
    const int gid = blockIdx.x * 256 + threadIdx.x;   // 0..65535 = b*2048+n*32+d
    float v = 0.f;
    for (int t = 0; t < NTILE_B; ++t) v += part[(size_t)t * CELLS + gid];
    float sq = v * v;
    #pragma unroll
    for (int m = 1; m < 32; m <<= 1) sq += __shfl_xor(sq, m, 64);  // sum over d
    const float scale = sqrtf(sq) / (1.0f + sq);
    const float o = v * scale;
    if (FINAL) out[gid] = o;
    else       os[gid] += o;
}

// =============================================================================
// ===== R8 fallback path -- used only if ws < ~320 MB =========================
// =============================================================================
#define BH    4
#define NBG   (B_/BH)
#define ITILE 8
#define NTILE (IN_/ITILE)
#define NBLK  (NTILE*NBG)
#define PCELLS ((size_t)BH*N_*D_)

__global__ __launch_bounds__(256)
void convert_kernel(const float4* __restrict__ W, uint4* __restrict__ W16)
{
    const size_t n8 = WELEMS / 8;
    const size_t stride = (size_t)gridDim.x * 256;
    for (size_t i = (size_t)blockIdx.x * 256 + threadIdx.x; i < n8; i += stride) {
        const float4 a = W[2 * i], b = W[2 * i + 1];
        uint4 o;
        o.x = rb(a.x) | (rb(a.y) << 16);
        o.y = rb(a.z) | (rb(a.w) << 16);
        o.z = rb(b.x) | (rb(b.y) << 16);
        o.w = rb(b.z) | (rb(b.w) << 16);
        W16[i] = o;
    }
}

template<bool FIRST>
__global__ __launch_bounds__(256, 1)
void route16_kernel(const float* __restrict__ x, const unsigned short* __restrict__ W16,
                    const float* __restrict__ os, float* __restrict__ part)
{
    __shared__ unsigned short uh_s[N_][D_][BH];
    __shared__ float logit_s[BH][N_];

    const int tid  = threadIdx.x;
    const int w    = tid >> 6;
    const int l    = tid & 63;
    const int d    = l & 31;
    const int hi   = l >> 5;
    const int slot = w * 2 + hi;

    const int virt = (blockIdx.x & 7) * (NBLK / 8) + (blockIdx.x >> 3);
    const int tile = virt / NBG;
    const int bg   = virt % NBG;
    const int b0   = bg * BH;
    const int i0   = tile * ITILE;

    float s_acc[8][BH];
    #pragma unroll
    for (int r = 0; r < 8; ++r)
        #pragma unroll
        for (int jb = 0; jb < BH; ++jb) s_acc[r][jb] = 0.f;

    const unsigned short* wb = W16 + (((size_t)slot * IN_ + i0) * D_ + d) * K_;

    for (int ii = 0; ii < ITILE; ++ii) {
        const float* xb = x + (size_t)b0 * (IN_ * K_) + (size_t)(i0 + ii) * K_;

        #pragma unroll
        for (int r = 0; r < 8; ++r) {
            const int n = r * 8 + slot;
            const unsigned short* wr = wb + (size_t)r * (8ull * IN_ * D_ * K_)
                                          + (size_t)ii * (D_ * K_);
            const uint4 plo = *(const uint4*)(wr);
            const uint4 phi = *(const uint4*)(wr + 8);
            float wf[16];
            wf[ 0]=blo(plo.x); wf[ 1]=bhi(plo.x); wf[ 2]=blo(plo.y); wf[ 3]=bhi(plo.y);
            wf[ 4]=blo(plo.z); wf[ 5]=bhi(plo.z); wf[ 6]=blo(plo.w); wf[ 7]=bhi(plo.w);
            wf[ 8]=blo(phi.x); wf[ 9]=bhi(phi.x); wf[10]=blo(phi.y); wf[11]=bhi(phi.y);
            wf[12]=blo(phi.z); wf[13]=bhi(phi.z); wf[14]=blo(phi.w); wf[15]=bhi(phi.w);

            float uh[BH];
            #pragma unroll
            for (int jb = 0; jb < BH; ++jb) {
                const float4 x0 = *(const float4*)(xb + (size_t)jb * (IN_ * K_) + 0);
                const float4 x1 = *(const float4*)(xb + (size_t)jb * (IN_ * K_) + 4);
                const float4 x2 = *(const float4*)(xb + (size_t)jb * (IN_ * K_) + 8);
                const float4 x3 = *(const float4*)(xb + (size_t)jb * (IN_ * K_) + 12);
                uh[jb] = wf[ 0]*x0.x + wf[ 1]*x0.y + wf[ 2]*x0.z + wf[ 3]*x0.w
                       + wf[ 4]*x1.x + wf[ 5]*x1.y + wf[ 6]*x1.z + wf[ 7]*x1.w
                       + wf[ 8]*x2.x + wf[ 9]*x2.y + wf[10]*x2.z + wf[11]*x2.w
                       + wf[12]*x3.x + wf[13]*x3.y + wf[14]*x3.z + wf[15]*x3.w;
            }

            if (FIRST) {
                #pragma unroll
                for (int jb = 0; jb < BH; ++jb) s_acc[r][jb] += uh[jb];
            } else {
                uint2 pk;
                pk.x = rb(uh[0]) | (rb(uh[1]) << 16);
                pk.y = rb(uh[2]) | (rb(uh[3]) << 16);
                *(uint2*)&uh_s[n][d][0] = pk;
                #pragma unroll
                for (int jb = 0; jb < BH; ++jb) {
                    float t = uh[jb] * os[((size_t)(b0 + jb) * N_ + n) * D_ + d];
                    #pragma unroll
                    for (int m = 1; m < 32; m <<= 1) t += __shfl_xor(t, m, 64);
                    if (d == 0) logit_s[jb][n] = t;
                }
            }
        }

        if (!FIRST) {
            __syncthreads();
            {
                const float v = logit_s[w][l];
                float mx = v;
                #pragma unroll
                for (int m = 1; m < 64; m <<= 1) mx = fmaxf(mx, __shfl_xor(mx, m, 64));
                const float e = exp2f((v - mx) * SM_SCALE);
                float sum = e;
                #pragma unroll
                for (int m = 1; m < 64; m <<= 1) sum += __shfl_xor(sum, m, 64);
                logit_s[w][l] = e / sum;
            }
            __syncthreads();
            #pragma unroll
            for (int r = 0; r < 8; ++r) {
                const int n = r * 8 + slot;
                const uint2 pk = *(const uint2*)&uh_s[n][d][0];
                s_acc[r][0] += logit_s[0][n] * blo(pk.x);
                s_acc[r][1] += logit_s[1][n] * bhi(pk.x);
                s_acc[r][2] += logit_s[2][n] * blo(pk.y);
                s_acc[r][3] += logit_s[3][n] * bhi(pk.y);
            }
            __syncthreads();
        }
    }

    const float scale = FIRST ? (1.0f / 64.0f) : 1.0f;
    float* myp = part + (size_t)virt * PCELLS;
    #pragma unroll
    for (int r = 0; r < 8; ++r) {
        const int n = r * 8 + slot;
        #pragma unroll
        for (int jb = 0; jb < BH; ++jb)
            myp[((size_t)jb * N_ + n) * D_ + d] = s_acc[r][jb] * scale;
    }
}

template<bool FINAL>
__global__ __launch_bounds__(256)
void finish_kernel(const float* __restrict__ part,
                   float* __restrict__ os, float* __restrict__ out)
{
    const int gid = blockIdx.x * 256 + threadIdx.x;
    const int b   = gid >> 11;
    const int rem = gid & 2047;
    const int bg = b >> 2, jb = b & 3;
    const float* p0 = part + (size_t)bg * PCELLS + (size_t)jb * (N_ * D_) + rem;
    float v = 0.f;
    for (int t = 0; t < NTILE; ++t) v += p0[(size_t)t * NBG * PCELLS];
    float sq = v * v;
    #pragma unroll
    for (int m = 1; m < 32; m <<= 1) sq += __shfl_xor(sq, m, 64);
    const float scale = sqrtf(sq) / (1.0f + sq);
    const float o = v * scale;
    if (FINAL) out[gid] = o;
    else       os[gid] += o;
}

extern "C" void kernel_launch(void* const* d_in, const int* in_sizes, int n_in,
                              void* d_out, int out_size, void* d_ws, size_t ws_size,
                              hipStream_t stream)
{
    const float* x = (const float*)d_in[0];
    const float* W = (const float*)d_in[1];
    float* out = (float*)d_out;

    const size_t partB_bytes = (size_t)NTILE_B * CELLS * 4;   // 64 MB
    const size_t need_new    = UH_BYTES + partB_bytes + CELLS * 4;

    if (ws_size >= need_new) {
        unsigned short* uhat = (unsigned short*)d_ws;
        float* part = (float*)((char*)d_ws + UH_BYTES);
        float* os   = part + (size_t)NTILE_B * CELLS;

        zero_kernel<<<CELLS / 1024, 256, 0, stream>>>((float4*)os);
        uhat_kernel<<<IN_ * 8, 256, 0, stream>>>(x, W, uhat);

        routeB_kernel<false><<<NBLK_B, 256, 0, stream>>>(uhat, nullptr, part);
        finishB_kernel<false><<<CELLS / 256, 256, 0, stream>>>(part, os, nullptr);
        routeB_kernel<true ><<<NBLK_B, 256, 0, stream>>>(uhat, os, part);
        finishB_kernel<false><<<CELLS / 256, 256, 0, stream>>>(part, os, nullptr);
        routeB_kernel<true ><<<NBLK_B, 256, 0, stream>>>(uhat, os, part);
        finishB_kernel<true ><<<CELLS / 256, 256, 0, stream>>>(part, nullptr, out);
        return;
    }

    // ---- R8 fallback (proven) ----
    const size_t w16_bytes = WELEMS * 2;
    unsigned short* W16 = (unsigned short*)d_ws;
    float* part = (float*)((char*)d_ws + w16_bytes);
    float* os   = part + (size_t)NBLK * PCELLS;

    zero_kernel<<<CELLS / 1024, 256, 0, stream>>>((float4*)os);
    convert_kernel<<<2048, 256, 0, stream>>>((const float4*)W, (uint4*)d_ws);

    for (int it = 0; it < 3; ++it) {
        if (it == 0) route16_kernel<true ><<<NBLK, 256, 0, stream>>>(x, W16, os, part);
        else         route16_kernel<false><<<NBLK, 256, 0, stream>>>(x, W16, os, part);
        if (it < 2)  finish_kernel<false><<<CELLS / 256, 256, 0, stream>>>(part, os, nullptr);
        else         finish_kernel<true ><<<CELLS / 256, 256, 0, stream>>>(part, nullptr, out);
    }
}

// Round 13
// 353.984 us; speedup vs baseline: 2.0160x; 1.3803x over previous
//
#include <hip/hip_runtime.h>

#define B_    32
#define N_    64
#define IN_   2048
#define D_    32
#define K_    16
#define CELLS  ((size_t)B_*N_*D_)      /* 65536 */
#define WELEMS ((size_t)N_*IN_*D_*K_)  /* 67108864 */
#define UH_ELEMS ((size_t)B_*IN_*N_*D_) /* 134217728 */
#define UH_BYTES (UH_ELEMS*2)          /* 256 MB */
#define T_B    16                       /* i's per routeB block */
#define NTILE_B (IN_/T_B)               /* 128 */
#define NBLK_B  (NTILE_B*8)             /* 1024 */

// softmax_e(v * INV_LOG2) == 2^((v-max) * (1/ln2)^2)
#define SM_SCALE 2.0813689810056077f

// ---- bf16 helpers (RNE) ----
__device__ __forceinline__ unsigned int rb(float f) {
    unsigned int u = __float_as_uint(f);
    return (u + 0x7fffu + ((u >> 16) & 1u)) >> 16;
}
__device__ __forceinline__ float blo(unsigned int u) { return __uint_as_float(u << 16); }
__device__ __forceinline__ float bhi(unsigned int u) { return __uint_as_float(u & 0xffff0000u); }

__device__ __forceinline__ float dot8(uint4 q, const float* o) {
    return blo(q.x)*o[0] + bhi(q.x)*o[1] + blo(q.y)*o[2] + bhi(q.y)*o[3]
         + blo(q.z)*o[4] + bhi(q.z)*o[5] + blo(q.w)*o[6] + bhi(q.w)*o[7];
}
__device__ __forceinline__ void acc8(float* s, uint4 q, float c) {
    s[0] += c*blo(q.x); s[1] += c*bhi(q.x); s[2] += c*blo(q.y); s[3] += c*bhi(q.y);
    s[4] += c*blo(q.z); s[5] += c*bhi(q.z); s[6] += c*blo(q.w); s[7] += c*bhi(q.w);
}

__global__ __launch_bounds__(256)
void zero_kernel(float4* __restrict__ os)
{
    os[blockIdx.x * 256 + threadIdx.x] = float4{0.f, 0.f, 0.f, 0.f};
}

// -----------------------------------------------------------------------------
// uhat_kernel: u_hat[i][b][n][d] = sum_k W[n,i,d,k]*x[b,i,k], bf16 store.
// R13 layout change: i-major. Each block's 32 b-stores land in ONE contiguous
// 128 KB [i]-plane (4 KB apart) instead of 8 MB apart -- R12 showed 2.8 TB/s
// (53% of achievable) with the 8 MB-strided write streams (HBM row thrash).
// Thread=(n,d), block=(i, n-chunk). W read once chip-wide, coalesced;
// x block-uniform -> scalar loads. VGPR ~24 (R12-measured), occ 86%.
// -----------------------------------------------------------------------------
__global__ __launch_bounds__(256, 1)
void uhat_kernel(const float* __restrict__ x, const float* __restrict__ W,
                 unsigned short* __restrict__ uhat)
{
    const int tid   = threadIdx.x;
    const int i     = blockIdx.x >> 3;
    const int chunk = blockIdx.x & 7;
    const int n     = chunk * 8 + (tid >> 5);
    const int d     = tid & 31;

    const float4* wp = (const float4*)(W + (((size_t)n * IN_ + i) * D_ + d) * K_);
    const float4 w0 = wp[0], w1 = wp[1], w2 = wp[2], w3 = wp[3];

    const float* xb = x + (size_t)i * K_;
    unsigned short* up = uhat + (size_t)i * (B_ * N_ * D_) + n * D_ + d;  // [i][b][n][d]

    #pragma unroll 8
    for (int b = 0; b < B_; ++b) {
        const float* xr = xb + (size_t)b * (IN_ * K_);   // block-uniform -> s_load
        const float4 x0 = *(const float4*)(xr);
        const float4 x1 = *(const float4*)(xr + 4);
        const float4 x2 = *(const float4*)(xr + 8);
        const float4 x3 = *(const float4*)(xr + 12);
        const float uh = w0.x*x0.x + w0.y*x0.y + w0.z*x0.z + w0.w*x0.w
                       + w1.x*x1.x + w1.y*x1.y + w1.z*x1.z + w1.w*x1.w
                       + w2.x*x2.x + w2.y*x2.y + w2.z*x2.z + w2.w*x2.w
                       + w3.x*x3.x + w3.y*x3.y + w3.z*x3.z + w3.w*x3.w;
        up[(size_t)b * (N_ * D_)] = (unsigned short)rb(uh);   // 4 KB b-stride
    }
}

// -----------------------------------------------------------------------------
// routeB_kernel: one routing pass reading u_hat[i][b][n][d] (bf16, single
// touch, contiguous per (i,b)). Thread=(b-in-group, n): 256 thr = 4b x 64n;
// block=(i-tile of 16, b-group). logit = thread-local dot over d (no
// shuffles); softmax over n = one 64-lane butterfly; s_acc[32] in regs.
// PASS=false: iteration 0, c = 1/64 uniform (no os read).
// -----------------------------------------------------------------------------
template<bool PASS>
__global__ __launch_bounds__(256, 1)
void routeB_kernel(const unsigned short* __restrict__ uhat,
                   const float* __restrict__ os, float* __restrict__ part)
{
    const int tid  = threadIdx.x;
    const int jb   = tid >> 6;          // wave = batch-in-group
    const int n    = tid & 63;          // lane = n
    const int tile = blockIdx.x >> 3;
    const int bg   = blockIdx.x & 7;
    const int b    = bg * 4 + jb;
    const int i0   = tile * T_B;

    float s_acc[D_];
    #pragma unroll
    for (int d = 0; d < D_; ++d) s_acc[d] = 0.f;

    float osr[D_];
    if (PASS) {
        const float4* op = (const float4*)(os + ((size_t)b * N_ + n) * D_);
        #pragma unroll
        for (int d4 = 0; d4 < 8; ++d4) *(float4*)&osr[d4 * 4] = op[d4];
    }

    const unsigned short* up = uhat + ((size_t)i0 * B_ + b) * (N_ * D_) + n * D_;

    #pragma unroll 2
    for (int ii = 0; ii < T_B; ++ii) {
        const uint4 q0 = *(const uint4*)(up);
        const uint4 q1 = *(const uint4*)(up + 8);
        const uint4 q2 = *(const uint4*)(up + 16);
        const uint4 q3 = *(const uint4*)(up + 24);
        up += (size_t)B_ * N_ * D_;     // next i, same b

        if (PASS) {
            float t = dot8(q0, osr) + dot8(q1, osr + 8)
                    + dot8(q2, osr + 16) + dot8(q3, osr + 24);
            float mx = t;
            #pragma unroll
            for (int m = 1; m < 64; m <<= 1) mx = fmaxf(mx, __shfl_xor(mx, m, 64));
            const float e = exp2f((t - mx) * SM_SCALE);
            float sum = e;
            #pragma unroll
            for (int m = 1; m < 64; m <<= 1) sum += __shfl_xor(sum, m, 64);
            const float c = e / sum;
            acc8(s_acc, q0, c); acc8(s_acc + 8,  q1, c);
            acc8(s_acc + 16, q2, c); acc8(s_acc + 24, q3, c);
        } else {
            acc8(s_acc, q0, 1.f); acc8(s_acc + 8,  q1, 1.f);
            acc8(s_acc + 16, q2, 1.f); acc8(s_acc + 24, q3, 1.f);
        }
    }

    const float scale = PASS ? 1.f : (1.f / 64.f);
    float4* myp = (float4*)(part + (size_t)tile * CELLS + ((size_t)b * N_ + n) * D_);
    #pragma unroll
    for (int d4 = 0; d4 < 8; ++d4) {
        float4 v;
        v.x = s_acc[d4*4 + 0] * scale; v.y = s_acc[d4*4 + 1] * scale;
        v.z = s_acc[d4*4 + 2] * scale; v.w = s_acc[d4*4 + 3] * scale;
        myp[d4] = v;
    }
}

// -----------------------------------------------------------------------------
// finishB_kernel: s = sum over NTILE_B tile-partials; out = squash(s);
// FINAL=false: os += out; FINAL=true: write d_out.
// -----------------------------------------------------------------------------
template<bool FINAL>
__global__ __launch_bounds__(256)
void finishB_kernel(const float* __restrict__ part,
                    float* __restrict__ os, float* __restrict__ out)
{
    const int gid = blockIdx.x * 256 + threadIdx.x;   // 0..65535 = b*2048+n*32+d
    float v = 0.f;
    for (int t = 0; t < NTILE_B; ++t) v += part[(size_t)t * CELLS + gid];
    float sq = v * v;
    #pragma unroll
    for (int m = 1; m < 32; m <<= 1) sq += __shfl_xor(sq, m, 64);  // sum over d
    const float scale = sqrtf(sq) / (1.0f + sq);
    const float o = v * scale;
    if (FINAL) out[gid] = o;
    else       os[gid] += o;
}

// =============================================================================
// ===== R8 fallback path -- used only if ws < ~320 MB =========================
// =============================================================================
#define BH    4
#define NBG   (B_/BH)
#define ITILE 8
#define NTILE (IN_/ITILE)
#define NBLK  (NTILE*NBG)
#define PCELLS ((size_t)BH*N_*D_)

__global__ __launch_bounds__(256)
void convert_kernel(const float4* __restrict__ W, uint4* __restrict__ W16)
{
    const size_t n8 = WELEMS / 8;
    const size_t stride = (size_t)gridDim.x * 256;
    for (size_t i = (size_t)blockIdx.x * 256 + threadIdx.x; i < n8; i += stride) {
        const float4 a = W[2 * i], b = W[2 * i + 1];
        uint4 o;
        o.x = rb(a.x) | (rb(a.y) << 16);
        o.y = rb(a.z) | (rb(a.w) << 16);
        o.z = rb(b.x) | (rb(b.y) << 16);
        o.w = rb(b.z) | (rb(b.w) << 16);
        W16[i] = o;
    }
}

template<bool FIRST>
__global__ __launch_bounds__(256, 1)
void route16_kernel(const float* __restrict__ x, const unsigned short* __restrict__ W16,
                    const float* __restrict__ os, float* __restrict__ part)
{
    __shared__ unsigned short uh_s[N_][D_][BH];
    __shared__ float logit_s[BH][N_];

    const int tid  = threadIdx.x;
    const int w    = tid >> 6;
    const int l    = tid & 63;
    const int d    = l & 31;
    const int hi   = l >> 5;
    const int slot = w * 2 + hi;

    const int virt = (blockIdx.x & 7) * (NBLK / 8) + (blockIdx.x >> 3);
    const int tile = virt / NBG;
    const int bg   = virt % NBG;
    const int b0   = bg * BH;
    const int i0   = tile * ITILE;

    float s_acc[8][BH];
    #pragma unroll
    for (int r = 0; r < 8; ++r)
        #pragma unroll
        for (int jb = 0; jb < BH; ++jb) s_acc[r][jb] = 0.f;

    const unsigned short* wb = W16 + (((size_t)slot * IN_ + i0) * D_ + d) * K_;

    for (int ii = 0; ii < ITILE; ++ii) {
        const float* xb = x + (size_t)b0 * (IN_ * K_) + (size_t)(i0 + ii) * K_;

        #pragma unroll
        for (int r = 0; r < 8; ++r) {
            const int n = r * 8 + slot;
            const unsigned short* wr = wb + (size_t)r * (8ull * IN_ * D_ * K_)
                                          + (size_t)ii * (D_ * K_);
            const uint4 plo = *(const uint4*)(wr);
            const uint4 phi = *(const uint4*)(wr + 8);
            float wf[16];
            wf[ 0]=blo(plo.x); wf[ 1]=bhi(plo.x); wf[ 2]=blo(plo.y); wf[ 3]=bhi(plo.y);
            wf[ 4]=blo(plo.z); wf[ 5]=bhi(plo.z); wf[ 6]=blo(plo.w); wf[ 7]=bhi(plo.w);
            wf[ 8]=blo(phi.x); wf[ 9]=bhi(phi.x); wf[10]=blo(phi.y); wf[11]=bhi(phi.y);
            wf[12]=blo(phi.z); wf[13]=bhi(phi.z); wf[14]=blo(phi.w); wf[15]=bhi(phi.w);

            float uh[BH];
            #pragma unroll
            for (int jb = 0; jb < BH; ++jb) {
                const float4 x0 = *(const float4*)(xb + (size_t)jb * (IN_ * K_) + 0);
                const float4 x1 = *(const float4*)(xb + (size_t)jb * (IN_ * K_) + 4);
                const float4 x2 = *(const float4*)(xb + (size_t)jb * (IN_ * K_) + 8);
                const float4 x3 = *(const float4*)(xb + (size_t)jb * (IN_ * K_) + 12);
                uh[jb] = wf[ 0]*x0.x + wf[ 1]*x0.y + wf[ 2]*x0.z + wf[ 3]*x0.w
                       + wf[ 4]*x1.x + wf[ 5]*x1.y + wf[ 6]*x1.z + wf[ 7]*x1.w
                       + wf[ 8]*x2.x + wf[ 9]*x2.y + wf[10]*x2.z + wf[11]*x2.w
                       + wf[12]*x3.x + wf[13]*x3.y + wf[14]*x3.z + wf[15]*x3.w;
            }

            if (FIRST) {
                #pragma unroll
                for (int jb = 0; jb < BH; ++jb) s_acc[r][jb] += uh[jb];
            } else {
                uint2 pk;
                pk.x = rb(uh[0]) | (rb(uh[1]) << 16);
                pk.y = rb(uh[2]) | (rb(uh[3]) << 16);
                *(uint2*)&uh_s[n][d][0] = pk;
                #pragma unroll
                for (int jb = 0; jb < BH; ++jb) {
                    float t = uh[jb] * os[((size_t)(b0 + jb) * N_ + n) * D_ + d];
                    #pragma unroll
                    for (int m = 1; m < 32; m <<= 1) t += __shfl_xor(t, m, 64);
                    if (d == 0) logit_s[jb][n] = t;
                }
            }
        }

        if (!FIRST) {
            __syncthreads();
            {
                const float v = logit_s[w][l];
                float mx = v;
                #pragma unroll
                for (int m = 1; m < 64; m <<= 1) mx = fmaxf(mx, __shfl_xor(mx, m, 64));
                const float e = exp2f((v - mx) * SM_SCALE);
                float sum = e;
                #pragma unroll
                for (int m = 1; m < 64; m <<= 1) sum += __shfl_xor(sum, m, 64);
                logit_s[w][l] = e / sum;
            }
            __syncthreads();
            #pragma unroll
            for (int r = 0; r < 8; ++r) {
                const int n = r * 8 + slot;
                const uint2 pk = *(const uint2*)&uh_s[n][d][0];
                s_acc[r][0] += logit_s[0][n] * blo(pk.x);
                s_acc[r][1] += logit_s[1][n] * bhi(pk.x);
                s_acc[r][2] += logit_s[2][n] * blo(pk.y);
                s_acc[r][3] += logit_s[3][n] * bhi(pk.y);
            }
            __syncthreads();
        }
    }

    const float scale = FIRST ? (1.0f / 64.0f) : 1.0f;
    float* myp = part + (size_t)virt * PCELLS;
    #pragma unroll
    for (int r = 0; r < 8; ++r) {
        const int n = r * 8 + slot;
        #pragma unroll
        for (int jb = 0; jb < BH; ++jb)
            myp[((size_t)jb * N_ + n) * D_ + d] = s_acc[r][jb] * scale;
    }
}

template<bool FINAL>
__global__ __launch_bounds__(256)
void finish_kernel(const float* __restrict__ part,
                   float* __restrict__ os, float* __restrict__ out)
{
    const int gid = blockIdx.x * 256 + threadIdx.x;
    const int b   = gid >> 11;
    const int rem = gid & 2047;
    const int bg = b >> 2, jb = b & 3;
    const float* p0 = part + (size_t)bg * PCELLS + (size_t)jb * (N_ * D_) + rem;
    float v = 0.f;
    for (int t = 0; t < NTILE; ++t) v += p0[(size_t)t * NBG * PCELLS];
    float sq = v * v;
    #pragma unroll
    for (int m = 1; m < 32; m <<= 1) sq += __shfl_xor(sq, m, 64);
    const float scale = sqrtf(sq) / (1.0f + sq);
    const float o = v * scale;
    if (FINAL) out[gid] = o;
    else       os[gid] += o;
}

extern "C" void kernel_launch(void* const* d_in, const int* in_sizes, int n_in,
                              void* d_out, int out_size, void* d_ws, size_t ws_size,
                              hipStream_t stream)
{
    const float* x = (const float*)d_in[0];
    const float* W = (const float*)d_in[1];
    float* out = (float*)d_out;

    const size_t partB_bytes = (size_t)NTILE_B * CELLS * 4;   // 32 MB
    const size_t need_new    = UH_BYTES + partB_bytes + CELLS * 4;

    if (ws_size >= need_new) {
        unsigned short* uhat = (unsigned short*)d_ws;
        float* part = (float*)((char*)d_ws + UH_BYTES);
        float* os   = part + (size_t)NTILE_B * CELLS;

        zero_kernel<<<CELLS / 1024, 256, 0, stream>>>((float4*)os);
        uhat_kernel<<<IN_ * 8, 256, 0, stream>>>(x, W, uhat);

        routeB_kernel<false><<<NBLK_B, 256, 0, stream>>>(uhat, nullptr, part);
        finishB_kernel<false><<<CELLS / 256, 256, 0, stream>>>(part, os, nullptr);
        routeB_kernel<true ><<<NBLK_B, 256, 0, stream>>>(uhat, os, part);
        finishB_kernel<false><<<CELLS / 256, 256, 0, stream>>>(part, os, nullptr);
        routeB_kernel<true ><<<NBLK_B, 256, 0, stream>>>(uhat, os, part);
        finishB_kernel<true ><<<CELLS / 256, 256, 0, stream>>>(part, nullptr, out);
        return;
    }

    // ---- R8 fallback (proven) ----
    const size_t w16_bytes = WELEMS * 2;
    unsigned short* W16 = (unsigned short*)d_ws;
    float* part = (float*)((char*)d_ws + w16_bytes);
    float* os   = part + (size_t)NBLK * PCELLS;

    zero_kernel<<<CELLS / 1024, 256, 0, stream>>>((float4*)os);
    convert_kernel<<<2048, 256, 0, stream>>>((const float4*)W, (uint4*)d_ws);

    for (int it = 0; it < 3; ++it) {
        if (it == 0) route16_kernel<true ><<<NBLK, 256, 0, stream>>>(x, W16, os, part);
        else         route16_kernel<false><<<NBLK, 256, 0, stream>>>(x, W16, os, part);
        if (it < 2)  finish_kernel<false><<<CELLS / 256, 256, 0, stream>>>(part, os, nullptr);
        else         finish_kernel<true ><<<CELLS / 256, 256, 0, stream>>>(part, nullptr, out);
    }
}

// Round 14
// 331.354 us; speedup vs baseline: 2.1537x; 1.0683x over previous
//
#include <hip/hip_runtime.h>

#define B_    32
#define N_    64
#define IN_   2048
#define D_    32
#define K_    16
#define CELLS  ((size_t)B_*N_*D_)      /* 65536 */
#define WELEMS ((size_t)N_*IN_*D_*K_)  /* 67108864 */
#define UH_ELEMS ((size_t)B_*IN_*N_*D_) /* 134217728 */
#define UH_BYTES (UH_ELEMS*2)          /* 256 MB */
#define T_B    16                       /* i's per routeB block */
#define NTILE_B (IN_/T_B)               /* 128 */
#define NBLK_B  (NTILE_B*8)             /* 1024 */

// softmax_e(v * INV_LOG2) == 2^((v-max) * (1/ln2)^2)
#define SM_SCALE 2.0813689810056077f

// ---- bf16 helpers (RNE) ----
__device__ __forceinline__ unsigned int rb(float f) {
    unsigned int u = __float_as_uint(f);
    return (u + 0x7fffu + ((u >> 16) & 1u)) >> 16;
}
__device__ __forceinline__ float blo(unsigned int u) { return __uint_as_float(u << 16); }
__device__ __forceinline__ float bhi(unsigned int u) { return __uint_as_float(u & 0xffff0000u); }

__device__ __forceinline__ float dot8(uint4 q, const float* o) {
    return blo(q.x)*o[0] + bhi(q.x)*o[1] + blo(q.y)*o[2] + bhi(q.y)*o[3]
         + blo(q.z)*o[4] + bhi(q.z)*o[5] + blo(q.w)*o[6] + bhi(q.w)*o[7];
}
__device__ __forceinline__ void acc8(float* s, uint4 q, float c) {
    s[0] += c*blo(q.x); s[1] += c*bhi(q.x); s[2] += c*blo(q.y); s[3] += c*bhi(q.y);
    s[4] += c*blo(q.z); s[5] += c*bhi(q.z); s[6] += c*blo(q.w); s[7] += c*bhi(q.w);
}

__global__ __launch_bounds__(256)
void zero_kernel(float4* __restrict__ os)
{
    os[blockIdx.x * 256 + threadIdx.x] = float4{0.f, 0.f, 0.f, 0.f};
}

// -----------------------------------------------------------------------------
// uhat_kernel: u_hat[i][b][n][d] = sum_k W[n,i,d,k]*x[b,i,k], bf16 store.
// R14 change: x slice staged in LDS. R13 disproved store-locality (8MB->4KB
// stride changed nothing); counters (VALUBusy 27%, occ 86%, HBM 35%) point at
// the per-b scalar s_load chain: buffering 8 b's of x needs 128 SGPRs (>102
// avail) so the compiler runs ~2 b's ahead -> ~200cy L2 stall per b vs 32cy
// FMA. LDS broadcast reads (uniform addr, conflict-free) pipeline on lgkmcnt.
// -----------------------------------------------------------------------------
__global__ __launch_bounds__(256, 1)
void uhat_kernel(const float* __restrict__ x, const float* __restrict__ W,
                 unsigned short* __restrict__ uhat)
{
    __shared__ float x_s[B_][K_];   // 2 KB: x[b][k] for this block's i

    const int tid   = threadIdx.x;
    const int i     = blockIdx.x >> 3;
    const int chunk = blockIdx.x & 7;
    const int n     = chunk * 8 + (tid >> 5);
    const int d     = tid & 31;

    {   // stage x[:, i, :]: 512 floats, 256 threads x float2, coalesced
        const int idx = tid * 2;
        const int b = idx >> 4, k = idx & 15;
        *(float2*)&x_s[b][k] =
            *(const float2*)(x + (size_t)b * (IN_ * K_) + (size_t)i * K_ + k);
    }

    const float4* wp = (const float4*)(W + (((size_t)n * IN_ + i) * D_ + d) * K_);
    const float4 w0 = wp[0], w1 = wp[1], w2 = wp[2], w3 = wp[3];

    __syncthreads();

    unsigned short* up = uhat + (size_t)i * (B_ * N_ * D_) + n * D_ + d;  // [i][b][n][d]

    #pragma unroll 8
    for (int b = 0; b < B_; ++b) {
        const float4 x0 = ((const float4*)x_s[b])[0];   // uniform addr -> broadcast
        const float4 x1 = ((const float4*)x_s[b])[1];
        const float4 x2 = ((const float4*)x_s[b])[2];
        const float4 x3 = ((const float4*)x_s[b])[3];
        const float uh = w0.x*x0.x + w0.y*x0.y + w0.z*x0.z + w0.w*x0.w
                       + w1.x*x1.x + w1.y*x1.y + w1.z*x1.z + w1.w*x1.w
                       + w2.x*x2.x + w2.y*x2.y + w2.z*x2.z + w2.w*x2.w
                       + w3.x*x3.x + w3.y*x3.y + w3.z*x3.z + w3.w*x3.w;
        up[(size_t)b * (N_ * D_)] = (unsigned short)rb(uh);
    }
}

// -----------------------------------------------------------------------------
// routeB_kernel: one routing pass reading u_hat[i][b][n][d] (bf16, single
// touch, contiguous per (i,b)). Thread=(b-in-group, n): 256 thr = 4b x 64n;
// block=(i-tile of 16, b-group). logit = thread-local dot over d; softmax
// over n = one 64-lane butterfly; s_acc[32] in regs. R13-measured ~55us/pass
// (85% of its 46us stream floor). PASS=false: iter 0, c = 1/64 uniform.
// -----------------------------------------------------------------------------
template<bool PASS>
__global__ __launch_bounds__(256, 1)
void routeB_kernel(const unsigned short* __restrict__ uhat,
                   const float* __restrict__ os, float* __restrict__ part)
{
    const int tid  = threadIdx.x;
    const int jb   = tid >> 6;          // wave = batch-in-group
    const int n    = tid & 63;          // lane = n
    const int tile = blockIdx.x >> 3;
    const int bg   = blockIdx.x & 7;
    const int b    = bg * 4 + jb;
    const int i0   = tile * T_B;

    float s_acc[D_];
    #pragma unroll
    for (int d = 0; d < D_; ++d) s_acc[d] = 0.f;

    float osr[D_];
    if (PASS) {
        const float4* op = (const float4*)(os + ((size_t)b * N_ + n) * D_);
        #pragma unroll
        for (int d4 = 0; d4 < 8; ++d4) *(float4*)&osr[d4 * 4] = op[d4];
    }

    const unsigned short* up = uhat + ((size_t)i0 * B_ + b) * (N_ * D_) + n * D_;

    #pragma unroll 2
    for (int ii = 0; ii < T_B; ++ii) {
        const uint4 q0 = *(const uint4*)(up);
        const uint4 q1 = *(const uint4*)(up + 8);
        const uint4 q2 = *(const uint4*)(up + 16);
        const uint4 q3 = *(const uint4*)(up + 24);
        up += (size_t)B_ * N_ * D_;     // next i, same b

        if (PASS) {
            float t = dot8(q0, osr) + dot8(q1, osr + 8)
                    + dot8(q2, osr + 16) + dot8(q3, osr + 24);
            float mx = t;
            #pragma unroll
            for (int m = 1; m < 64; m <<= 1) mx = fmaxf(mx, __shfl_xor(mx, m, 64));
            const float e = exp2f((t - mx) * SM_SCALE);
            float sum = e;
            #pragma unroll
            for (int m = 1; m < 64; m <<= 1) sum += __shfl_xor(sum, m, 64);
            const float c = e / sum;
            acc8(s_acc, q0, c); acc8(s_acc + 8,  q1, c);
            acc8(s_acc + 16, q2, c); acc8(s_acc + 24, q3, c);
        } else {
            acc8(s_acc, q0, 1.f); acc8(s_acc + 8,  q1, 1.f);
            acc8(s_acc + 16, q2, 1.f); acc8(s_acc + 24, q3, 1.f);
        }
    }

    const float scale = PASS ? 1.f : (1.f / 64.f);
    float4* myp = (float4*)(part + (size_t)tile * CELLS + ((size_t)b * N_ + n) * D_);
    #pragma unroll
    for (int d4 = 0; d4 < 8; ++d4) {
        float4 v;
        v.x = s_acc[d4*4 + 0] * scale; v.y = s_acc[d4*4 + 1] * scale;
        v.z = s_acc[d4*4 + 2] * scale; v.w = s_acc[d4*4 + 3] * scale;
        myp[d4] = v;
    }
}

// -----------------------------------------------------------------------------
// finishB_kernel: s = sum over NTILE_B tile-partials; out = squash(s);
// FINAL=false: os += out; FINAL=true: write d_out.
// -----------------------------------------------------------------------------
template<bool FINAL>
__global__ __launch_bounds__(256)
void finishB_kernel(const float* __restrict__ part,
                    float* __restrict__ os, float* __restrict__ out)
{
    const int gid = blockIdx.x * 256 + threadIdx.x;   // 0..65535 = b*2048+n*32+d
    float v = 0.f;
    for (int t = 0; t < NTILE_B; ++t) v += part[(size_t)t * CELLS + gid];
    float sq = v * v;
    #pragma unroll
    for (int m = 1; m < 32; m <<= 1) sq += __shfl_xor(sq, m, 64);  // sum over d
    const float scale = sqrtf(sq) / (1.0f + sq);
    const float o = v * scale;
    if (FINAL) out[gid] = o;
    else       os[gid] += o;
}

// =============================================================================
// ===== R8 fallback path -- used only if ws < ~320 MB =========================
// =============================================================================
#define BH    4
#define NBG   (B_/BH)
#define ITILE 8
#define NTILE (IN_/ITILE)
#define NBLK  (NTILE*NBG)
#define PCELLS ((size_t)BH*N_*D_)

__global__ __launch_bounds__(256)
void convert_kernel(const float4* __restrict__ W, uint4* __restrict__ W16)
{
    const size_t n8 = WELEMS / 8;
    const size_t stride = (size_t)gridDim.x * 256;
    for (size_t i = (size_t)blockIdx.x * 256 + threadIdx.x; i < n8; i += stride) {
        const float4 a = W[2 * i], b = W[2 * i + 1];
        uint4 o;
        o.x = rb(a.x) | (rb(a.y) << 16);
        o.y = rb(a.z) | (rb(a.w) << 16);
        o.z = rb(b.x) | (rb(b.y) << 16);
        o.w = rb(b.z) | (rb(b.w) << 16);
        W16[i] = o;
    }
}

template<bool FIRST>
__global__ __launch_bounds__(256, 1)
void route16_kernel(const float* __restrict__ x, const unsigned short* __restrict__ W16,
                    const float* __restrict__ os, float* __restrict__ part)
{
    __shared__ unsigned short uh_s[N_][D_][BH];
    __shared__ float logit_s[BH][N_];

    const int tid  = threadIdx.x;
    const int w    = tid >> 6;
    const int l    = tid & 63;
    const int d    = l & 31;
    const int hi   = l >> 5;
    const int slot = w * 2 + hi;

    const int virt = (blockIdx.x & 7) * (NBLK / 8) + (blockIdx.x >> 3);
    const int tile = virt / NBG;
    const int bg   = virt % NBG;
    const int b0   = bg * BH;
    const int i0   = tile * ITILE;

    float s_acc[8][BH];
    #pragma unroll
    for (int r = 0; r < 8; ++r)
        #pragma unroll
        for (int jb = 0; jb < BH; ++jb) s_acc[r][jb] = 0.f;

    const unsigned short* wb = W16 + (((size_t)slot * IN_ + i0) * D_ + d) * K_;

    for (int ii = 0; ii < ITILE; ++ii) {
        const float* xb = x + (size_t)b0 * (IN_ * K_) + (size_t)(i0 + ii) * K_;

        #pragma unroll
        for (int r = 0; r < 8; ++r) {
            const int n = r * 8 + slot;
            const unsigned short* wr = wb + (size_t)r * (8ull * IN_ * D_ * K_)
                                          + (size_t)ii * (D_ * K_);
            const uint4 plo = *(const uint4*)(wr);
            const uint4 phi = *(const uint4*)(wr + 8);
            float wf[16];
            wf[ 0]=blo(plo.x); wf[ 1]=bhi(plo.x); wf[ 2]=blo(plo.y); wf[ 3]=bhi(plo.y);
            wf[ 4]=blo(plo.z); wf[ 5]=bhi(plo.z); wf[ 6]=blo(plo.w); wf[ 7]=bhi(plo.w);
            wf[ 8]=blo(phi.x); wf[ 9]=bhi(phi.x); wf[10]=blo(phi.y); wf[11]=bhi(phi.y);
            wf[12]=blo(phi.z); wf[13]=bhi(phi.z); wf[14]=blo(phi.w); wf[15]=bhi(phi.w);

            float uh[BH];
            #pragma unroll
            for (int jb = 0; jb < BH; ++jb) {
                const float4 x0 = *(const float4*)(xb + (size_t)jb * (IN_ * K_) + 0);
                const float4 x1 = *(const float4*)(xb + (size_t)jb * (IN_ * K_) + 4);
                const float4 x2 = *(const float4*)(xb + (size_t)jb * (IN_ * K_) + 8);
                const float4 x3 = *(const float4*)(xb + (size_t)jb * (IN_ * K_) + 12);
                uh[jb] = wf[ 0]*x0.x + wf[ 1]*x0.y + wf[ 2]*x0.z + wf[ 3]*x0.w
                       + wf[ 4]*x1.x + wf[ 5]*x1.y + wf[ 6]*x1.z + wf[ 7]*x1.w
                       + wf[ 8]*x2.x + wf[ 9]*x2.y + wf[10]*x2.z + wf[11]*x2.w
                       + wf[12]*x3.x + wf[13]*x3.y + wf[14]*x3.z + wf[15]*x3.w;
            }

            if (FIRST) {
                #pragma unroll
                for (int jb = 0; jb < BH; ++jb) s_acc[r][jb] += uh[jb];
            } else {
                uint2 pk;
                pk.x = rb(uh[0]) | (rb(uh[1]) << 16);
                pk.y = rb(uh[2]) | (rb(uh[3]) << 16);
                *(uint2*)&uh_s[n][d][0] = pk;
                #pragma unroll
                for (int jb = 0; jb < BH; ++jb) {
                    float t = uh[jb] * os[((size_t)(b0 + jb) * N_ + n) * D_ + d];
                    #pragma unroll
                    for (int m = 1; m < 32; m <<= 1) t += __shfl_xor(t, m, 64);
                    if (d == 0) logit_s[jb][n] = t;
                }
            }
        }

        if (!FIRST) {
            __syncthreads();
            {
                const float v = logit_s[w][l];
                float mx = v;
                #pragma unroll
                for (int m = 1; m < 64; m <<= 1) mx = fmaxf(mx, __shfl_xor(mx, m, 64));
                const float e = exp2f((v - mx) * SM_SCALE);
                float sum = e;
                #pragma unroll
                for (int m = 1; m < 64; m <<= 1) sum += __shfl_xor(sum, m, 64);
                logit_s[w][l] = e / sum;
            }
            __syncthreads();
            #pragma unroll
            for (int r = 0; r < 8; ++r) {
                const int n = r * 8 + slot;
                const uint2 pk = *(const uint2*)&uh_s[n][d][0];
                s_acc[r][0] += logit_s[0][n] * blo(pk.x);
                s_acc[r][1] += logit_s[1][n] * bhi(pk.x);
                s_acc[r][2] += logit_s[2][n] * blo(pk.y);
                s_acc[r][3] += logit_s[3][n] * bhi(pk.y);
            }
            __syncthreads();
        }
    }

    const float scale = FIRST ? (1.0f / 64.0f) : 1.0f;
    float* myp = part + (size_t)virt * PCELLS;
    #pragma unroll
    for (int r = 0; r < 8; ++r) {
        const int n = r * 8 + slot;
        #pragma unroll
        for (int jb = 0; jb < BH; ++jb)
            myp[((size_t)jb * N_ + n) * D_ + d] = s_acc[r][jb] * scale;
    }
}

template<bool FINAL>
__global__ __launch_bounds__(256)
void finish_kernel(const float* __restrict__ part,
                   float* __restrict__ os, float* __restrict__ out)
{
    const int gid = blockIdx.x * 256 + threadIdx.x;
    const int b   = gid >> 11;
    const int rem = gid & 2047;
    const int bg = b >> 2, jb = b & 3;
    const float* p0 = part + (size_t)bg * PCELLS + (size_t)jb * (N_ * D_) + rem;
    float v = 0.f;
    for (int t = 0; t < NTILE; ++t) v += p0[(size_t)t * NBG * PCELLS];
    float sq = v * v;
    #pragma unroll
    for (int m = 1; m < 32; m <<= 1) sq += __shfl_xor(sq, m, 64);
    const float scale = sqrtf(sq) / (1.0f + sq);
    const float o = v * scale;
    if (FINAL) out[gid] = o;
    else       os[gid] += o;
}

extern "C" void kernel_launch(void* const* d_in, const int* in_sizes, int n_in,
                              void* d_out, int out_size, void* d_ws, size_t ws_size,
                              hipStream_t stream)
{
    const float* x = (const float*)d_in[0];
    const float* W = (const float*)d_in[1];
    float* out = (float*)d_out;

    const size_t partB_bytes = (size_t)NTILE_B * CELLS * 4;   // 32 MB
    const size_t need_new    = UH_BYTES + partB_bytes + CELLS * 4;

    if (ws_size >= need_new) {
        unsigned short* uhat = (unsigned short*)d_ws;
        float* part = (float*)((char*)d_ws + UH_BYTES);
        float* os   = part + (size_t)NTILE_B * CELLS;

        zero_kernel<<<CELLS / 1024, 256, 0, stream>>>((float4*)os);
        uhat_kernel<<<IN_ * 8, 256, 0, stream>>>(x, W, uhat);

        routeB_kernel<false><<<NBLK_B, 256, 0, stream>>>(uhat, nullptr, part);
        finishB_kernel<false><<<CELLS / 256, 256, 0, stream>>>(part, os, nullptr);
        routeB_kernel<true ><<<NBLK_B, 256, 0, stream>>>(uhat, os, part);
        finishB_kernel<false><<<CELLS / 256, 256, 0, stream>>>(part, os, nullptr);
        routeB_kernel<true ><<<NBLK_B, 256, 0, stream>>>(uhat, os, part);
        finishB_kernel<true ><<<CELLS / 256, 256, 0, stream>>>(part, nullptr, out);
        return;
    }

    // ---- R8 fallback (proven) ----
    const size_t w16_bytes = WELEMS * 2;
    unsigned short* W16 = (unsigned short*)d_ws;
    float* part = (float*)((char*)d_ws + w16_bytes);
    float* os   = part + (size_t)NBLK * PCELLS;

    zero_kernel<<<CELLS / 1024, 256, 0, stream>>>((float4*)os);
    convert_kernel<<<2048, 256, 0, stream>>>((const float4*)W, (uint4*)d_ws);

    for (int it = 0; it < 3; ++it) {
        if (it == 0) route16_kernel<true ><<<NBLK, 256, 0, stream>>>(x, W16, os, part);
        else         route16_kernel<false><<<NBLK, 256, 0, stream>>>(x, W16, os, part);
        if (it < 2)  finish_kernel<false><<<CELLS / 256, 256, 0, stream>>>(part, os, nullptr);
        else         finish_kernel<true ><<<CELLS / 256, 256, 0, stream>>>(part, nullptr, out);
    }
}